// Round 5
// baseline (1333.383 us; speedup 1.0000x reference)
//
#include <hip/hip_runtime.h>
#include <hip/hip_fp16.h>

#define NN 500000
#define NE 16000000
#define DCH 2048               // dst nodes per chunk
#define NCHUNK 245             // ceil(NN/DCH)
#define SSL 8192               // src nodes per slice
#define NSLICE 62              // ceil(NN/SSL)
#define NBINS2 (NCHUNK*NSLICE) // 15190
#define CAP2 1408              // per-bin cap: mean 1074, sd 33 -> +10 sigma
#define PBLK 253
#define PITER 248              // 253*256*248 >= NE

// ===========================================================================
// Src record: float2 { h01(fp16x2), h23(fp16x2) } = 8B. tab padded to
// NSLICE*SSL records so slice staging needs no guards.
// Edge record: uint32 = (dl << 13) | sl   (dl < 2048, sl < 8192).
// All random access is LDS; all global access coalesced.
// ===========================================================================

// Prep layer 1: tab[i] = packed h (4xfp16); adv[i]; resid = x@resW+resb.
__global__ __launch_bounds__(256) void k_prep1(
    const float* __restrict__ x, const float* __restrict__ W1,
    const float* __restrict__ a_dst,
    const float* __restrict__ resW, const float* __restrict__ resb,
    const unsigned* __restrict__ ei,
    float* __restrict__ resid, float2* __restrict__ tab,
    float* __restrict__ adv, float* __restrict__ sm,
    int* __restrict__ flag, int* __restrict__ gcnt)
{
  __shared__ float sW1[64], sWr[64], sv[8];
  int t = threadIdx.x;
  if (t < 64) { sW1[t] = W1[t]; sWr[t] = resW[t]; }
  if (t < 4)  { sv[t] = a_dst[t]; sv[4+t] = resb[t]; }
  __syncthreads();
  int i = blockIdx.x * 256 + t;
  if (i == 0) {
    sm[0]=0.f; sm[1]=0.f; sm[2]=0.f; sm[3]=0.f;
    int* smi = (int*)sm; smi[4]=0; smi[5]=0; smi[6]=0; smi[7]=0;
    unsigned o = 0;
    for (int k = 1; k < 64; k += 2) o |= ei[k];   // int64 => odd words zero
    *flag = (o == 0) ? 1 : 0;
  }
  if (i < NBINS2) gcnt[i] = 0;
  if (i >= NN) return;
  const float4* xp = (const float4*)(x + (size_t)i * 16);
  float4 a0 = xp[0], a1 = xp[1], a2 = xp[2], a3 = xp[3];
  float xr[16] = {a0.x,a0.y,a0.z,a0.w, a1.x,a1.y,a1.z,a1.w,
                  a2.x,a2.y,a2.z,a2.w, a3.x,a3.y,a3.z,a3.w};
  float h[4] = {0.f,0.f,0.f,0.f};
  float r[4] = {sv[4], sv[5], sv[6], sv[7]};
#pragma unroll
  for (int k = 0; k < 16; k++) {
    float xv = xr[k];
#pragma unroll
    for (int c = 0; c < 4; c++) {
      h[c] = fmaf(xv, sW1[k*4+c], h[c]);
      r[c] = fmaf(xv, sWr[k*4+c], r[c]);
    }
  }
  float ad_ = h[0]*sv[0] + h[1]*sv[1] + h[2]*sv[2] + h[3]*sv[3];
  *(float4*)(resid + (size_t)i*4) = make_float4(r[0], r[1], r[2], r[3]);
  __half2 p01 = __floats2half2_rn(h[0], h[1]);
  __half2 p23 = __floats2half2_rn(h[2], h[3]);
  float2 rec; rec.x = *(float*)&p01; rec.y = *(float*)&p23;
  tab[i] = rec;
  adv[i] = ad_;
}

// Partition edges into (dst-chunk, src-slice) bins; packed 4B records.
__global__ __launch_bounds__(256) void k_part(
    const unsigned* __restrict__ ei, const int* __restrict__ flag,
    int* __restrict__ gcnt, unsigned* __restrict__ eout)
{
  __shared__ int hist[NBINS2];
  int t = threadIdx.x;
  for (int b = t; b < NBINS2; b += 256) hist[b] = 0;
  __syncthreads();
  const bool f64 = (*flag != 0);
  size_t base = (size_t)blockIdx.x * (PITER * 256);
  for (int k = 0; k < PITER; k++) {
    size_t e = base + (size_t)k * 256 + t;
    if (e < NE) {
      unsigned s, d;
      if (f64) { s = ((const uint2*)ei)[e].x; d = ((const uint2*)ei)[(size_t)NE + e].x; }
      else     { s = ei[e]; d = ei[(size_t)NE + e]; }
      atomicAdd(&hist[(d >> 11) * NSLICE + (s >> 13)], 1);
    }
  }
  __syncthreads();
  for (int b = t; b < NBINS2; b += 256) {
    int c = hist[b];
    int g = (c > 0) ? atomicAdd(&gcnt[b], c) : 0;
    hist[b] = b * CAP2 + g;            // rebase to global write cursor
  }
  __syncthreads();
  for (int k = 0; k < PITER; k++) {
    size_t e = base + (size_t)k * 256 + t;
    if (e < NE) {
      unsigned s, d;
      if (f64) { s = ((const uint2*)ei)[e].x; d = ((const uint2*)ei)[(size_t)NE + e].x; }
      else     { s = ei[e]; d = ei[(size_t)NE + e]; }
      int bin = (d >> 11) * NSLICE + (s >> 13);
      int pos = atomicAdd(&hist[bin], 1);
      if (pos < (bin + 1) * CAP2)      // capacity guard (deterministic drop)
        eout[pos] = ((d & 2047u) << 13) | (s & 8191u);
    }
  }
}

// Per-layer reduce: one block per dst-chunk; self-loops seed LDS acc; loop
// over src-slices: stage 64KB slice of tab into LDS (coalesced) + prefetch
// this slice's edge words (coalesced); process edges LDS-only.
#define PROC2(w) { \
  int dl = (int)((w) >> 13); \
  float2 rr = st2[(w) & 8191u]; \
  float2 f01 = __half22float2(*(const __half2*)&rr.x); \
  float2 f23 = __half22float2(*(const __half2*)&rr.y); \
  float as_ = f01.x*sa0 + f01.y*sa1 + f23.x*sa2 + f23.y*sa3; \
  float v = as_ + sadv[dl]; v = v > 0.f ? v : 0.2f * v; \
  float ex = __expf(v); \
  atomicAdd(&acc[dl*5+0], ex*f01.x); \
  atomicAdd(&acc[dl*5+1], ex*f01.y); \
  atomicAdd(&acc[dl*5+2], ex*f23.x); \
  atomicAdd(&acc[dl*5+3], ex*f23.y); \
  atomicAdd(&acc[dl*5+4], ex); }

__global__ __launch_bounds__(1024) void k_reduce(
    const unsigned* __restrict__ edges, const int* __restrict__ gcnt,
    const float2* __restrict__ tab, const float* __restrict__ adv,
    const float* __restrict__ a_src, const float* __restrict__ bias,
    float* __restrict__ hout, float* __restrict__ pool)
{
  __shared__ float4 stab[SSL/2];      // 64KB slice table
  __shared__ float acc[DCH*5];        // 40KB accumulators
  __shared__ float sadv[DCH];         // 8KB
  __shared__ int scnt[NSLICE];
  __shared__ float rs[16][4], rm[16][4];
  int t = threadIdx.x;
  int b = blockIdx.x;
  int base = b * DCH;
  int nloc = NN - base; if (nloc > DCH) nloc = DCH;
  const float sa0 = a_src[0], sa1 = a_src[1], sa2 = a_src[2], sa3 = a_src[3];
  // self-loop seeding
  for (int i = t; i < DCH; i += 1024) {
    if (i < nloc) {
      float2 r = tab[base + i];
      float2 f01 = __half22float2(*(const __half2*)&r.x);
      float2 f23 = __half22float2(*(const __half2*)&r.y);
      float ad_ = adv[base + i];
      sadv[i] = ad_;
      float as_ = f01.x*sa0 + f01.y*sa1 + f23.x*sa2 + f23.y*sa3;
      float v = as_ + ad_; v = v > 0.f ? v : 0.2f * v;
      float ex = __expf(v);
      acc[i*5+0]=ex*f01.x; acc[i*5+1]=ex*f01.y;
      acc[i*5+2]=ex*f23.x; acc[i*5+3]=ex*f23.y;
      acc[i*5+4]=ex;
    } else {
      sadv[i] = 0.f;
      acc[i*5+0]=0.f; acc[i*5+1]=0.f; acc[i*5+2]=0.f; acc[i*5+3]=0.f;
      acc[i*5+4]=1.f;
    }
  }
  if (t < NSLICE) scnt[t] = gcnt[b * NSLICE + t];
  const float4* tf4 = (const float4*)tab;   // padded to NSLICE*SSL records
  __syncthreads();
  for (int s = 0; s < NSLICE; s++) {
    // issue slice staging loads (coalesced, no guard: tab padded)
    size_t sb = (size_t)s * 4096;
    float4 r0 = tf4[sb + t];
    float4 r1 = tf4[sb + t + 1024];
    float4 r2 = tf4[sb + t + 2048];
    float4 r3 = tf4[sb + t + 3072];
    // prefetch this slice's edge words (coalesced); overlaps staging latency
    int cnt = scnt[s]; if (cnt > CAP2) cnt = CAP2;
    const unsigned* eb = edges + (size_t)(b * NSLICE + s) * CAP2;
    unsigned w0 = 0xFFFFFFFFu, w1 = 0xFFFFFFFFu;
    if (t < cnt) w0 = eb[t];
    if (t + 1024 < cnt) w1 = eb[t + 1024];
    stab[t] = r0; stab[t+1024] = r1; stab[t+2048] = r2; stab[t+3072] = r3;
    __syncthreads();
    const float2* st2 = (const float2*)stab;
    if (w0 != 0xFFFFFFFFu) PROC2(w0);
    if (w1 != 0xFFFFFFFFu) PROC2(w1);
    __syncthreads();
  }
  // finalize + pool
  float b0 = bias[0], b1_ = bias[1], b2_ = bias[2], b3_ = bias[3];
  float sv[4] = {0.f,0.f,0.f,0.f};
  float mv[4] = {0.f,0.f,0.f,0.f};
  for (int i = t; i < nloc; i += 1024) {
    float inv = 1.f / acc[i*5+4];
    float h0 = fmaxf(acc[i*5+0]*inv + b0, 0.f);
    float h1 = fmaxf(acc[i*5+1]*inv + b1_, 0.f);
    float h2 = fmaxf(acc[i*5+2]*inv + b2_, 0.f);
    float h3 = fmaxf(acc[i*5+3]*inv + b3_, 0.f);
    *(float4*)(hout + 4*(size_t)(base+i)) = make_float4(h0,h1,h2,h3);
    sv[0]+=h0; sv[1]+=h1; sv[2]+=h2; sv[3]+=h3;
    mv[0]=fmaxf(mv[0],h0); mv[1]=fmaxf(mv[1],h1);
    mv[2]=fmaxf(mv[2],h2); mv[3]=fmaxf(mv[3],h3);
  }
#pragma unroll
  for (int off = 32; off > 0; off >>= 1) {
#pragma unroll
    for (int c = 0; c < 4; c++) {
      sv[c] += __shfl_down(sv[c], off);
      mv[c] = fmaxf(mv[c], __shfl_down(mv[c], off));
    }
  }
  int w = t >> 6, lane = t & 63;
  if (lane == 0)
    for (int c = 0; c < 4; c++) { rs[w][c] = sv[c]; rm[w][c] = mv[c]; }
  __syncthreads();
  if (t == 0) {
    for (int c = 0; c < 4; c++) {
      float s0 = 0.f, m0 = 0.f;
      for (int k = 0; k < 16; k++) { s0 += rs[k][c]; m0 = fmaxf(m0, rm[k][c]); }
      atomicAdd(pool + c, s0);
      atomicMax((int*)pool + 4 + c, __float_as_int(m0));
    }
  }
}

// Prep layer 2: h2 = hb @ W2g (gate folded), pack tab; reset sm pools.
__global__ __launch_bounds__(256) void k_prep2(
    const float* __restrict__ hin, const float* __restrict__ W2g,
    const float* __restrict__ a_dst,
    float2* __restrict__ tab, float* __restrict__ adv, float* __restrict__ sm)
{
  __shared__ float sW[16], sa[4];
  int t = threadIdx.x;
  if (t < 16) sW[t] = W2g[t];
  if (t < 4) sa[t] = a_dst[t];
  __syncthreads();
  int i = blockIdx.x * 256 + t;
  if (i == 0) {
    sm[0]=0.f; sm[1]=0.f; sm[2]=0.f; sm[3]=0.f;
    int* smi = (int*)sm; smi[4]=0; smi[5]=0; smi[6]=0; smi[7]=0;
  }
  if (i >= NN) return;
  float4 hr = *(const float4*)(hin + (size_t)i*4);
  float hvv[4] = {hr.x, hr.y, hr.z, hr.w};
  float h[4] = {0.f, 0.f, 0.f, 0.f};
#pragma unroll
  for (int k = 0; k < 4; k++)
#pragma unroll
    for (int c = 0; c < 4; c++) h[c] = fmaf(hvv[k], sW[k*4+c], h[c]);
  float ad_ = h[0]*sa[0] + h[1]*sa[1] + h[2]*sa[2] + h[3]*sa[3];
  __half2 p01 = __floats2half2_rn(h[0], h[1]);
  __half2 p23 = __floats2half2_rn(h[2], h[3]);
  float2 rec; rec.x = *(float*)&p01; rec.y = *(float*)&p23;
  tab[i] = rec;
  adv[i] = ad_;
}

// Channel-attention gates (fold into downstream weights).
__global__ void k_gate1(const float* __restrict__ pool,
                        const float* __restrict__ w1, const float* __restrict__ w2,
                        const float* __restrict__ W2, float* __restrict__ W2g)
{
  if (threadIdx.x != 0) return;
  const int* pi = (const int*)pool;
  float avg[4], mx[4], gate[4];
  for (int c = 0; c < 4; c++) {
    avg[c] = pool[c] * (1.0f / NN);
    mx[c] = __int_as_float(pi[4 + c]);
  }
  float ta[2], tm[2];
  for (int j = 0; j < 2; j++) {
    float a = 0.f, m = 0.f;
    for (int c = 0; c < 4; c++) { a += avg[c] * w1[c*2+j]; m += mx[c] * w1[c*2+j]; }
    ta[j] = fmaxf(a, 0.f); tm[j] = fmaxf(m, 0.f);
  }
  for (int c = 0; c < 4; c++) {
    float g = 0.f;
    for (int j = 0; j < 2; j++) g += (ta[j] + tm[j]) * w2[j*4+c];
    gate[c] = 1.f / (1.f + __expf(-g));
  }
  for (int k = 0; k < 4; k++)
    for (int c = 0; c < 4; c++)
      W2g[k*4+c] = gate[k] * W2[k*4+c];
}

__global__ void k_gate2(const float* __restrict__ pool,
                        const float* __restrict__ w1, const float* __restrict__ w2,
                        const float* __restrict__ fcW, float* __restrict__ fcg)
{
  if (threadIdx.x != 0) return;
  const int* pi = (const int*)pool;
  float avg[4], mx[4], gate[4];
  for (int c = 0; c < 4; c++) {
    avg[c] = pool[c] * (1.0f / NN);
    mx[c] = __int_as_float(pi[4 + c]);
  }
  float ta[2], tm[2];
  for (int j = 0; j < 2; j++) {
    float a = 0.f, m = 0.f;
    for (int c = 0; c < 4; c++) { a += avg[c] * w1[c*2+j]; m += mx[c] * w1[c*2+j]; }
    ta[j] = fmaxf(a, 0.f); tm[j] = fmaxf(m, 0.f);
  }
  for (int c = 0; c < 4; c++) {
    float g = 0.f;
    for (int j = 0; j < 2; j++) g += (ta[j] + tm[j]) * w2[j*4+c];
    gate[c] = 1.f / (1.f + __expf(-g));
  }
  for (int c = 0; c < 4; c++) fcg[c] = gate[c] * fcW[c];
}

__global__ __launch_bounds__(256) void k_final(
    const float* __restrict__ g, const float* __restrict__ resid,
    const float* __restrict__ fcg, const float* __restrict__ fcW,
    const float* __restrict__ fcb, float* __restrict__ out)
{
  int i = blockIdx.x * 256 + threadIdx.x;
  if (i >= NN) return;
  float4 gv = *(const float4*)(g + (size_t)i*4);
  float4 rv = *(const float4*)(resid + (size_t)i*4);
  float acc = fcb[0]
    + gv.x*fcg[0] + gv.y*fcg[1] + gv.z*fcg[2] + gv.w*fcg[3]
    + rv.x*fcW[0] + rv.y*fcW[1] + rv.z*fcW[2] + rv.w*fcW[3];
  out[i] = 1.f / (1.f + __expf(-acc));
}

// ===========================================================================
// FALLBACK PATH (global-atomic version) if ws_size is too small.
// ===========================================================================
__global__ __launch_bounds__(256) void k_prep1f(
    const float* __restrict__ x, const float* __restrict__ W1,
    const float* __restrict__ a_src, const float* __restrict__ a_dst,
    const float* __restrict__ resW, const float* __restrict__ resb,
    const unsigned* __restrict__ ei,
    float* __restrict__ resid, float* __restrict__ h1,
    float* __restrict__ asv, float* __restrict__ adv,
    float* __restrict__ num, float* __restrict__ den,
    float* __restrict__ sm, int* __restrict__ flag)
{
  __shared__ float sW1[64], sWr[64], sv[12];
  int t = threadIdx.x;
  if (t < 64) { sW1[t] = W1[t]; sWr[t] = resW[t]; }
  if (t < 4)  { sv[t] = a_src[t]; sv[4+t] = a_dst[t]; sv[8+t] = resb[t]; }
  __syncthreads();
  int i = blockIdx.x * 256 + t;
  if (i == 0) {
    sm[0]=0.f; sm[1]=0.f; sm[2]=0.f; sm[3]=0.f;
    int* smi = (int*)sm; smi[4]=0; smi[5]=0; smi[6]=0; smi[7]=0;
    unsigned o = 0;
    for (int k = 1; k < 64; k += 2) o |= ei[k];
    *flag = (o == 0) ? 1 : 0;
  }
  if (i >= NN) return;
  const float4* xp = (const float4*)(x + (size_t)i * 16);
  float4 a0 = xp[0], a1 = xp[1], a2 = xp[2], a3 = xp[3];
  float xr[16] = {a0.x,a0.y,a0.z,a0.w, a1.x,a1.y,a1.z,a1.w,
                  a2.x,a2.y,a2.z,a2.w, a3.x,a3.y,a3.z,a3.w};
  float h[4] = {0.f,0.f,0.f,0.f};
  float r[4] = {sv[8], sv[9], sv[10], sv[11]};
#pragma unroll
  for (int k = 0; k < 16; k++) {
    float xv = xr[k];
#pragma unroll
    for (int c = 0; c < 4; c++) {
      h[c] = fmaf(xv, sW1[k*4+c], h[c]);
      r[c] = fmaf(xv, sWr[k*4+c], r[c]);
    }
  }
  float as_ = h[0]*sv[0] + h[1]*sv[1] + h[2]*sv[2] + h[3]*sv[3];
  float ad_ = h[0]*sv[4] + h[1]*sv[5] + h[2]*sv[6] + h[3]*sv[7];
  float e = as_ + ad_;
  e = e > 0.f ? e : 0.2f * e;
  float ex = __expf(e);
  *(float4*)(resid + (size_t)i*4) = make_float4(r[0], r[1], r[2], r[3]);
  *(float4*)(h1    + (size_t)i*4) = make_float4(h[0], h[1], h[2], h[3]);
  asv[i] = as_; adv[i] = ad_;
  den[i] = ex;
  *(float4*)(num + (size_t)i*4) = make_float4(ex*h[0], ex*h[1], ex*h[2], ex*h[3]);
}

__global__ __launch_bounds__(256) void k_edgef(
    const unsigned* __restrict__ ei, const int* __restrict__ flag,
    const float* __restrict__ asv, const float* __restrict__ adv,
    const float* __restrict__ h, float* __restrict__ num, float* __restrict__ den)
{
  int e = blockIdx.x * 256 + threadIdx.x;
  if (e >= NE) return;
  int s, d;
  if (*flag) {
    s = (int)ei[2 * (size_t)e];
    d = (int)ei[2 * ((size_t)NE + (size_t)e)];
  } else {
    s = (int)ei[e];
    d = (int)ei[(size_t)NE + (size_t)e];
  }
  float v = asv[s] + adv[d];
  v = v > 0.f ? v : 0.2f * v;
  float ex = __expf(v);
  float4 hs = *(const float4*)(h + 4 * (size_t)s);
  float* np = num + 4 * (size_t)d;
  atomicAdd(den + d, ex);
  atomicAdd(np + 0, ex * hs.x);
  atomicAdd(np + 1, ex * hs.y);
  atomicAdd(np + 2, ex * hs.z);
  atomicAdd(np + 3, ex * hs.w);
}

__global__ __launch_bounds__(256) void k_finishf(
    const float* __restrict__ num, const float* __restrict__ den,
    const float* __restrict__ b, float* __restrict__ hout, float* __restrict__ pool)
{
  int i = blockIdx.x * 256 + threadIdx.x;
  float hv[4] = {0.f, 0.f, 0.f, 0.f};
  if (i < NN) {
    float inv = 1.f / den[i];
    float4 nm = *(const float4*)(num + (size_t)i*4);
    hv[0] = fmaxf(nm.x * inv + b[0], 0.f);
    hv[1] = fmaxf(nm.y * inv + b[1], 0.f);
    hv[2] = fmaxf(nm.z * inv + b[2], 0.f);
    hv[3] = fmaxf(nm.w * inv + b[3], 0.f);
    *(float4*)(hout + (size_t)i*4) = make_float4(hv[0], hv[1], hv[2], hv[3]);
  }
  float sv[4] = {hv[0], hv[1], hv[2], hv[3]};
  float mv[4] = {hv[0], hv[1], hv[2], hv[3]};
#pragma unroll
  for (int off = 32; off > 0; off >>= 1) {
#pragma unroll
    for (int c = 0; c < 4; c++) {
      sv[c] += __shfl_down(sv[c], off);
      mv[c] = fmaxf(mv[c], __shfl_down(mv[c], off));
    }
  }
  __shared__ float rs[4][4], rm[4][4];
  int w = threadIdx.x >> 6, lane = threadIdx.x & 63;
  if (lane == 0)
    for (int c = 0; c < 4; c++) { rs[w][c] = sv[c]; rm[w][c] = mv[c]; }
  __syncthreads();
  if (threadIdx.x == 0) {
    for (int c = 0; c < 4; c++) {
      float s0 = rs[0][c] + rs[1][c] + rs[2][c] + rs[3][c];
      float m0 = fmaxf(fmaxf(rm[0][c], rm[1][c]), fmaxf(rm[2][c], rm[3][c]));
      atomicAdd(pool + c, s0);
      atomicMax((int*)pool + 4 + c, __float_as_int(m0));
    }
  }
}

__global__ __launch_bounds__(256) void k_prep2f(
    const float* __restrict__ hin, const float* __restrict__ W2g,
    const float* __restrict__ a_src, const float* __restrict__ a_dst,
    float* __restrict__ h2, float* __restrict__ asv, float* __restrict__ adv,
    float* __restrict__ num, float* __restrict__ den, float* __restrict__ sm)
{
  __shared__ float sW[16], sa[8];
  int t = threadIdx.x;
  if (t < 16) sW[t] = W2g[t];
  if (t < 4) { sa[t] = a_src[t]; sa[4+t] = a_dst[t]; }
  __syncthreads();
  int i = blockIdx.x * 256 + t;
  if (i == 0) {
    sm[0]=0.f; sm[1]=0.f; sm[2]=0.f; sm[3]=0.f;
    int* smi = (int*)sm; smi[4]=0; smi[5]=0; smi[6]=0; smi[7]=0;
  }
  if (i >= NN) return;
  float4 hr = *(const float4*)(hin + (size_t)i*4);
  float hvv[4] = {hr.x, hr.y, hr.z, hr.w};
  float h[4] = {0.f, 0.f, 0.f, 0.f};
#pragma unroll
  for (int k = 0; k < 4; k++)
#pragma unroll
    for (int c = 0; c < 4; c++) h[c] = fmaf(hvv[k], sW[k*4+c], h[c]);
  float as_ = h[0]*sa[0] + h[1]*sa[1] + h[2]*sa[2] + h[3]*sa[3];
  float ad_ = h[0]*sa[4] + h[1]*sa[5] + h[2]*sa[6] + h[3]*sa[7];
  float e = as_ + ad_;
  e = e > 0.f ? e : 0.2f * e;
  float ex = __expf(e);
  *(float4*)(h2 + (size_t)i*4) = make_float4(h[0], h[1], h[2], h[3]);
  asv[i] = as_; adv[i] = ad_;
  den[i] = ex;
  *(float4*)(num + (size_t)i*4) = make_float4(ex*h[0], ex*h[1], ex*h[2], ex*h[3]);
}

// ===========================================================================
extern "C" void kernel_launch(void* const* d_in, const int* in_sizes, int n_in,
                              void* d_out, int out_size, void* d_ws, size_t ws_size,
                              hipStream_t stream)
{
  const float*    x    = (const float*)d_in[0];
  const unsigned* ei   = (const unsigned*)d_in[1];
  const float*    W1   = (const float*)d_in[2];
  const float*    as1  = (const float*)d_in[3];
  const float*    ad1  = (const float*)d_in[4];
  const float*    b1   = (const float*)d_in[5];
  const float*    W2   = (const float*)d_in[6];
  const float*    as2  = (const float*)d_in[7];
  const float*    ad2  = (const float*)d_in[8];
  const float*    b2   = (const float*)d_in[9];
  const float*    c1w1 = (const float*)d_in[10];
  const float*    c1w2 = (const float*)d_in[11];
  const float*    c2w1 = (const float*)d_in[12];
  const float*    c2w2 = (const float*)d_in[13];
  const float*    resW = (const float*)d_in[14];
  const float*    resb = (const float*)d_in[15];
  const float*    fcW  = (const float*)d_in[16];
  const float*    fcb  = (const float*)d_in[17];
  float* out = (float*)d_out;

  dim3 blk(256);
  dim3 gn((NN + 255) / 256);      // 1954
  dim3 ge((NE + 255) / 256);

  char* p = (char*)d_ws;
  auto alloc = [&](size_t bytes) { char* r = p; p += (bytes + 255) & ~(size_t)255; return r; };
  float*    resid = (float*)alloc((size_t)NN * 4 * 4);
  float2*   tab   = (float2*)alloc((size_t)NSLICE * SSL * 8);   // padded
  float*    adv   = (float*)alloc((size_t)NN * 4);
  float*    hb    = (float*)alloc((size_t)NN * 4 * 4);
  float*    sm    = (float*)alloc(64 * 4);
  int*      flag  = (int*)alloc(256);
  int*      gcnt  = (int*)alloc((size_t)NBINS2 * 4);
  unsigned* edges = (unsigned*)alloc((size_t)NBINS2 * CAP2 * 4);
  size_t need = (size_t)(p - (char*)d_ws);

  if (ws_size >= need) {
    hipLaunchKernelGGL(k_prep1, gn, blk, 0, stream, x, W1, ad1, resW, resb, ei,
                       resid, tab, adv, sm, flag, gcnt);
    hipLaunchKernelGGL(k_part, dim3(PBLK), blk, 0, stream, ei, flag, gcnt, edges);
    hipLaunchKernelGGL(k_reduce, dim3(NCHUNK), dim3(1024), 0, stream, edges, gcnt,
                       tab, adv, as1, b1, hb, sm);
    hipLaunchKernelGGL(k_gate1, dim3(1), dim3(64), 0, stream, sm, c1w1, c1w2, W2, sm + 8);
    hipLaunchKernelGGL(k_prep2, gn, blk, 0, stream, hb, sm + 8, ad2, tab, adv, sm);
    hipLaunchKernelGGL(k_reduce, dim3(NCHUNK), dim3(1024), 0, stream, edges, gcnt,
                       tab, adv, as2, b2, hb, sm);
    hipLaunchKernelGGL(k_gate2, dim3(1), dim3(64), 0, stream, sm, c2w1, c2w2, fcW, sm + 24);
    hipLaunchKernelGGL(k_final, gn, blk, 0, stream, hb, resid, sm + 24, fcW, fcb, out);
  } else {
    float* ws2   = (float*)d_ws;
    float* residf= ws2;  ws2 += (size_t)NN * 4;
    float* h1    = ws2;  ws2 += (size_t)NN * 4;
    float* asb   = ws2;  ws2 += NN;
    float* adb   = ws2;  ws2 += NN;
    float* num   = ws2;  ws2 += (size_t)NN * 4;
    float* den   = ws2;  ws2 += NN;
    float* hbf   = ws2;  ws2 += (size_t)NN * 4;
    float* smf   = ws2;  ws2 += 64;
    int* flagf = (int*)ws2;

    hipLaunchKernelGGL(k_prep1f, gn, blk, 0, stream, x, W1, as1, ad1, resW, resb, ei,
                       residf, h1, asb, adb, num, den, smf, flagf);
    hipLaunchKernelGGL(k_edgef, ge, blk, 0, stream, ei, flagf, asb, adb, h1, num, den);
    hipLaunchKernelGGL(k_finishf, gn, blk, 0, stream, num, den, b1, hbf, smf);
    hipLaunchKernelGGL(k_gate1, dim3(1), dim3(64), 0, stream, smf, c1w1, c1w2, W2, smf + 8);
    hipLaunchKernelGGL(k_prep2f, gn, blk, 0, stream, hbf, smf + 8, as2, ad2,
                       h1, asb, adb, num, den, smf);
    hipLaunchKernelGGL(k_edgef, ge, blk, 0, stream, ei, flagf, asb, adb, h1, num, den);
    hipLaunchKernelGGL(k_finishf, gn, blk, 0, stream, num, den, b2, hbf, smf);
    hipLaunchKernelGGL(k_gate2, dim3(1), dim3(64), 0, stream, smf, c2w1, c2w2, fcW, smf + 24);
    hipLaunchKernelGGL(k_final, gn, blk, 0, stream, hbf, residf, smf + 24, fcW, fcb, out);
  }
}

// Round 6
// 1168.907 us; speedup vs baseline: 1.1407x; 1.1407x over previous
//
#include <hip/hip_runtime.h>
#include <hip/hip_fp16.h>

#define NN 500000
#define NE 16000000
#define BNODES 256
#define NBUK 1954              // ceil(NN / BNODES)
#define NBINS (2*NBUK)         // (dst bucket, src half)
#define SPLIT 250000           // src half threshold
#define SUBCAP 4864            // per-bin capacity: mean 4096, sd 64 -> +12 sigma
#define PBLK 1009
#define PITER 62               // PBLK*256*PITER >= NE

// ===========================================================================
// Src record: float2 { h01(fp16x2), h23(fp16x2) } = 8B -> 4MB table (L2-fits).
// Edge record: uint32 = (dl << 19) | src   (src < 2^19, dl < 256).
// Round-6 change: k_reduce reads tab + edge words via nontemporal loads
// (L1 bypass) to test the L1 outstanding-miss-queue hypothesis.
// ===========================================================================

__device__ __forceinline__ unsigned long long nt_u64(const void* p) {
  return __builtin_nontemporal_load((const unsigned long long*)p);
}
__device__ __forceinline__ unsigned nt_u32(const unsigned* p) {
  return __builtin_nontemporal_load(p);
}

// Prep layer 1: tab[i] = packed h (4xfp16); adv[i]; resid = x@resW+resb.
__global__ __launch_bounds__(256) void k_prep1(
    const float* __restrict__ x, const float* __restrict__ W1,
    const float* __restrict__ a_dst,
    const float* __restrict__ resW, const float* __restrict__ resb,
    const unsigned* __restrict__ ei,
    float* __restrict__ resid, float2* __restrict__ tab,
    float* __restrict__ adv, float* __restrict__ sm,
    int* __restrict__ flag, int* __restrict__ gcnt)
{
  __shared__ float sW1[64], sWr[64], sv[8];
  int t = threadIdx.x;
  if (t < 64) { sW1[t] = W1[t]; sWr[t] = resW[t]; }
  if (t < 4)  { sv[t] = a_dst[t]; sv[4+t] = resb[t]; }
  __syncthreads();
  int i = blockIdx.x * 256 + t;
  if (i == 0) {
    sm[0]=0.f; sm[1]=0.f; sm[2]=0.f; sm[3]=0.f;
    int* smi = (int*)sm; smi[4]=0; smi[5]=0; smi[6]=0; smi[7]=0;
    unsigned o = 0;
    for (int k = 1; k < 64; k += 2) o |= ei[k];   // int64 => odd words zero
    *flag = (o == 0) ? 1 : 0;
  }
  if (i < NBINS) gcnt[i] = 0;
  if (i >= NN) return;
  const float4* xp = (const float4*)(x + (size_t)i * 16);
  float4 a0 = xp[0], a1 = xp[1], a2 = xp[2], a3 = xp[3];
  float xr[16] = {a0.x,a0.y,a0.z,a0.w, a1.x,a1.y,a1.z,a1.w,
                  a2.x,a2.y,a2.z,a2.w, a3.x,a3.y,a3.z,a3.w};
  float h[4] = {0.f,0.f,0.f,0.f};
  float r[4] = {sv[4], sv[5], sv[6], sv[7]};
#pragma unroll
  for (int k = 0; k < 16; k++) {
    float xv = xr[k];
#pragma unroll
    for (int c = 0; c < 4; c++) {
      h[c] = fmaf(xv, sW1[k*4+c], h[c]);
      r[c] = fmaf(xv, sWr[k*4+c], r[c]);
    }
  }
  float ad_ = h[0]*sv[0] + h[1]*sv[1] + h[2]*sv[2] + h[3]*sv[3];
  *(float4*)(resid + (size_t)i*4) = make_float4(r[0], r[1], r[2], r[3]);
  __half2 p01 = __floats2half2_rn(h[0], h[1]);
  __half2 p23 = __floats2half2_rn(h[2], h[3]);
  float2 rec; rec.x = *(float*)&p01; rec.y = *(float*)&p23;
  tab[i] = rec;
  adv[i] = ad_;
}

// Partition edges into (dst-bucket, src-half) bins; packed 4B records.
__global__ __launch_bounds__(256) void k_part(
    const unsigned* __restrict__ ei, const int* __restrict__ flag,
    int* __restrict__ gcnt, unsigned* __restrict__ eout)
{
  __shared__ int hist[NBINS];
  int t = threadIdx.x;
  for (int b = t; b < NBINS; b += 256) hist[b] = 0;
  __syncthreads();
  const bool f64 = (*flag != 0);
  size_t base = (size_t)blockIdx.x * (PITER * 256);
  for (int k = 0; k < PITER; k++) {
    size_t e = base + (size_t)k * 256 + t;
    if (e < NE) {
      unsigned s, d;
      if (f64) { s = ((const uint2*)ei)[e].x; d = ((const uint2*)ei)[(size_t)NE + e].x; }
      else     { s = ei[e]; d = ei[(size_t)NE + e]; }
      atomicAdd(&hist[((d >> 8) << 1) | (s >= SPLIT)], 1);
    }
  }
  __syncthreads();
  for (int b = t; b < NBINS; b += 256) {
    int c = hist[b];
    int g = (c > 0) ? atomicAdd(&gcnt[b], c) : 0;
    hist[b] = b * SUBCAP + g;          // rebase to global write cursor
  }
  __syncthreads();
  for (int k = 0; k < PITER; k++) {
    size_t e = base + (size_t)k * 256 + t;
    if (e < NE) {
      unsigned s, d;
      if (f64) { s = ((const uint2*)ei)[e].x; d = ((const uint2*)ei)[(size_t)NE + e].x; }
      else     { s = ei[e]; d = ei[(size_t)NE + e]; }
      int bin = ((d >> 8) << 1) | (s >= SPLIT);
      int pos = atomicAdd(&hist[bin], 1);
      if (pos < (bin + 1) * SUBCAP)    // capacity guard (deterministic drop)
        eout[pos] = ((d & 255u) << 19) | s;
    }
  }
}

// Per-layer reduce: one block per dst bucket; self-loop seeds LDS acc;
// one 8B NT gather per edge, asv recomputed; 5 LDS atomics; finalize+pool.
#define PROC(w, u) { \
  int dl = (int)((w) >> 19) & 255; \
  unsigned ulo = (unsigned)(u), uhi = (unsigned)((u) >> 32); \
  float2 f01 = __half22float2(*(const __half2*)&ulo); \
  float2 f23 = __half22float2(*(const __half2*)&uhi); \
  float as_ = f01.x*sa0 + f01.y*sa1 + f23.x*sa2 + f23.y*sa3; \
  float v = as_ + sadv[dl]; v = v > 0.f ? v : 0.2f * v; \
  float ex = __expf(v); \
  atomicAdd(&acc[dl*5+0], ex*f01.x); \
  atomicAdd(&acc[dl*5+1], ex*f01.y); \
  atomicAdd(&acc[dl*5+2], ex*f23.x); \
  atomicAdd(&acc[dl*5+3], ex*f23.y); \
  atomicAdd(&acc[dl*5+4], ex); }

__global__ __launch_bounds__(256) void k_reduce(
    const unsigned* __restrict__ edges, const int* __restrict__ gcnt,
    const float2* __restrict__ tab, const float* __restrict__ adv,
    const float* __restrict__ a_src,
    const float* __restrict__ bias, float* __restrict__ hout,
    float* __restrict__ pool)
{
  __shared__ float acc[BNODES * 5];
  __shared__ float sadv[BNODES];
  int t = threadIdx.x;
  int b = blockIdx.x;
  int base = b * BNODES;
  int nloc = NN - base; if (nloc > BNODES) nloc = BNODES;
  const float sa0 = a_src[0], sa1 = a_src[1], sa2 = a_src[2], sa3 = a_src[3];
  if (t < nloc) {
    float2 r = tab[base + t];
    float2 f01 = __half22float2(*(const __half2*)&r.x);
    float2 f23 = __half22float2(*(const __half2*)&r.y);
    float ad_ = adv[base + t];
    sadv[t] = ad_;
    float as_ = f01.x*sa0 + f01.y*sa1 + f23.x*sa2 + f23.y*sa3;
    float v = as_ + ad_;
    v = v > 0.f ? v : 0.2f * v;
    float ex = __expf(v);
    acc[t*5+0] = ex*f01.x; acc[t*5+1] = ex*f01.y;
    acc[t*5+2] = ex*f23.x; acc[t*5+3] = ex*f23.y;
    acc[t*5+4] = ex;
  } else {
    sadv[t] = 0.f;
    acc[t*5+0]=0.f; acc[t*5+1]=0.f; acc[t*5+2]=0.f; acc[t*5+3]=0.f;
    acc[t*5+4] = 1.f;
  }
  __syncthreads();
#pragma unroll
  for (int half = 0; half < 2; half++) {
    int bin = b * 2 + half;
    int cnt = gcnt[bin]; if (cnt > SUBCAP) cnt = SUBCAP;
    const unsigned* eb = edges + (size_t)bin * SUBCAP;
    int j0 = 0;
    for (; j0 + 2048 <= cnt; j0 += 2048) {     // 8 independent NT gather chains
      unsigned w0 = nt_u32(eb + j0 + t);
      unsigned w1 = nt_u32(eb + j0 + t + 256);
      unsigned w2 = nt_u32(eb + j0 + t + 512);
      unsigned w3 = nt_u32(eb + j0 + t + 768);
      unsigned w4 = nt_u32(eb + j0 + t + 1024);
      unsigned w5 = nt_u32(eb + j0 + t + 1280);
      unsigned w6 = nt_u32(eb + j0 + t + 1536);
      unsigned w7 = nt_u32(eb + j0 + t + 1792);
      unsigned long long r0 = nt_u64(tab + (w0 & 0x7FFFFu));
      unsigned long long r1 = nt_u64(tab + (w1 & 0x7FFFFu));
      unsigned long long r2 = nt_u64(tab + (w2 & 0x7FFFFu));
      unsigned long long r3 = nt_u64(tab + (w3 & 0x7FFFFu));
      unsigned long long r4 = nt_u64(tab + (w4 & 0x7FFFFu));
      unsigned long long r5 = nt_u64(tab + (w5 & 0x7FFFFu));
      unsigned long long r6 = nt_u64(tab + (w6 & 0x7FFFFu));
      unsigned long long r7 = nt_u64(tab + (w7 & 0x7FFFFu));
      PROC(w0, r0); PROC(w1, r1); PROC(w2, r2); PROC(w3, r3);
      PROC(w4, r4); PROC(w5, r5); PROC(w6, r6); PROC(w7, r7);
    }
    for (; j0 + 1024 <= cnt; j0 += 1024) {     // 4-deep
      unsigned w0 = nt_u32(eb + j0 + t);
      unsigned w1 = nt_u32(eb + j0 + t + 256);
      unsigned w2 = nt_u32(eb + j0 + t + 512);
      unsigned w3 = nt_u32(eb + j0 + t + 768);
      unsigned long long r0 = nt_u64(tab + (w0 & 0x7FFFFu));
      unsigned long long r1 = nt_u64(tab + (w1 & 0x7FFFFu));
      unsigned long long r2 = nt_u64(tab + (w2 & 0x7FFFFu));
      unsigned long long r3 = nt_u64(tab + (w3 & 0x7FFFFu));
      PROC(w0, r0); PROC(w1, r1); PROC(w2, r2); PROC(w3, r3);
    }
    for (int j = j0 + t; j < cnt; j += 256) {
      unsigned w = nt_u32(eb + j);
      unsigned long long r = nt_u64(tab + (w & 0x7FFFFu));
      PROC(w, r);
    }
  }
  __syncthreads();
  float hv[4] = {0.f, 0.f, 0.f, 0.f};
  if (t < nloc) {
    float inv = 1.f / acc[t*5+4];
    hv[0] = fmaxf(acc[t*5+0]*inv + bias[0], 0.f);
    hv[1] = fmaxf(acc[t*5+1]*inv + bias[1], 0.f);
    hv[2] = fmaxf(acc[t*5+2]*inv + bias[2], 0.f);
    hv[3] = fmaxf(acc[t*5+3]*inv + bias[3], 0.f);
    *(float4*)(hout + 4*(size_t)(base+t)) = make_float4(hv[0],hv[1],hv[2],hv[3]);
  }
  float sv[4] = {hv[0], hv[1], hv[2], hv[3]};
  float mv[4] = {hv[0], hv[1], hv[2], hv[3]};
#pragma unroll
  for (int off = 32; off > 0; off >>= 1) {
#pragma unroll
    for (int c = 0; c < 4; c++) {
      sv[c] += __shfl_down(sv[c], off);
      mv[c] = fmaxf(mv[c], __shfl_down(mv[c], off));
    }
  }
  __shared__ float rs[4][4], rm[4][4];
  int w = threadIdx.x >> 6, lane = threadIdx.x & 63;
  if (lane == 0)
    for (int c = 0; c < 4; c++) { rs[w][c] = sv[c]; rm[w][c] = mv[c]; }
  __syncthreads();
  if (t == 0) {
    for (int c = 0; c < 4; c++) {
      float s0 = rs[0][c] + rs[1][c] + rs[2][c] + rs[3][c];
      float m0 = fmaxf(fmaxf(rm[0][c], rm[1][c]), fmaxf(rm[2][c], rm[3][c]));
      atomicAdd(pool + c, s0);
      atomicMax((int*)pool + 4 + c, __float_as_int(m0));
    }
  }
}

// Prep layer 2: h2 = hb @ W2g (gate folded), pack tab; reset sm pools.
__global__ __launch_bounds__(256) void k_prep2(
    const float* __restrict__ hin, const float* __restrict__ W2g,
    const float* __restrict__ a_dst,
    float2* __restrict__ tab, float* __restrict__ adv, float* __restrict__ sm)
{
  __shared__ float sW[16], sa[4];
  int t = threadIdx.x;
  if (t < 16) sW[t] = W2g[t];
  if (t < 4) sa[t] = a_dst[t];
  __syncthreads();
  int i = blockIdx.x * 256 + t;
  if (i == 0) {
    sm[0]=0.f; sm[1]=0.f; sm[2]=0.f; sm[3]=0.f;
    int* smi = (int*)sm; smi[4]=0; smi[5]=0; smi[6]=0; smi[7]=0;
  }
  if (i >= NN) return;
  float4 hr = *(const float4*)(hin + (size_t)i*4);
  float hvv[4] = {hr.x, hr.y, hr.z, hr.w};
  float h[4] = {0.f, 0.f, 0.f, 0.f};
#pragma unroll
  for (int k = 0; k < 4; k++)
#pragma unroll
    for (int c = 0; c < 4; c++) h[c] = fmaf(hvv[k], sW[k*4+c], h[c]);
  float ad_ = h[0]*sa[0] + h[1]*sa[1] + h[2]*sa[2] + h[3]*sa[3];
  __half2 p01 = __floats2half2_rn(h[0], h[1]);
  __half2 p23 = __floats2half2_rn(h[2], h[3]);
  float2 rec; rec.x = *(float*)&p01; rec.y = *(float*)&p23;
  tab[i] = rec;
  adv[i] = ad_;
}

// Channel-attention gates (fold into downstream weights).
__global__ void k_gate1(const float* __restrict__ pool,
                        const float* __restrict__ w1, const float* __restrict__ w2,
                        const float* __restrict__ W2, float* __restrict__ W2g)
{
  if (threadIdx.x != 0) return;
  const int* pi = (const int*)pool;
  float avg[4], mx[4], gate[4];
  for (int c = 0; c < 4; c++) {
    avg[c] = pool[c] * (1.0f / NN);
    mx[c] = __int_as_float(pi[4 + c]);
  }
  float ta[2], tm[2];
  for (int j = 0; j < 2; j++) {
    float a = 0.f, m = 0.f;
    for (int c = 0; c < 4; c++) { a += avg[c] * w1[c*2+j]; m += mx[c] * w1[c*2+j]; }
    ta[j] = fmaxf(a, 0.f); tm[j] = fmaxf(m, 0.f);
  }
  for (int c = 0; c < 4; c++) {
    float g = 0.f;
    for (int j = 0; j < 2; j++) g += (ta[j] + tm[j]) * w2[j*4+c];
    gate[c] = 1.f / (1.f + __expf(-g));
  }
  for (int k = 0; k < 4; k++)
    for (int c = 0; c < 4; c++)
      W2g[k*4+c] = gate[k] * W2[k*4+c];
}

__global__ void k_gate2(const float* __restrict__ pool,
                        const float* __restrict__ w1, const float* __restrict__ w2,
                        const float* __restrict__ fcW, float* __restrict__ fcg)
{
  if (threadIdx.x != 0) return;
  const int* pi = (const int*)pool;
  float avg[4], mx[4], gate[4];
  for (int c = 0; c < 4; c++) {
    avg[c] = pool[c] * (1.0f / NN);
    mx[c] = __int_as_float(pi[4 + c]);
  }
  float ta[2], tm[2];
  for (int j = 0; j < 2; j++) {
    float a = 0.f, m = 0.f;
    for (int c = 0; c < 4; c++) { a += avg[c] * w1[c*2+j]; m += mx[c] * w1[c*2+j]; }
    ta[j] = fmaxf(a, 0.f); tm[j] = fmaxf(m, 0.f);
  }
  for (int c = 0; c < 4; c++) {
    float g = 0.f;
    for (int j = 0; j < 2; j++) g += (ta[j] + tm[j]) * w2[j*4+c];
    gate[c] = 1.f / (1.f + __expf(-g));
  }
  for (int c = 0; c < 4; c++) fcg[c] = gate[c] * fcW[c];
}

__global__ __launch_bounds__(256) void k_final(
    const float* __restrict__ g, const float* __restrict__ resid,
    const float* __restrict__ fcg, const float* __restrict__ fcW,
    const float* __restrict__ fcb, float* __restrict__ out)
{
  int i = blockIdx.x * 256 + threadIdx.x;
  if (i >= NN) return;
  float4 gv = *(const float4*)(g + (size_t)i*4);
  float4 rv = *(const float4*)(resid + (size_t)i*4);
  float acc = fcb[0]
    + gv.x*fcg[0] + gv.y*fcg[1] + gv.z*fcg[2] + gv.w*fcg[3]
    + rv.x*fcW[0] + rv.y*fcW[1] + rv.z*fcW[2] + rv.w*fcW[3];
  out[i] = 1.f / (1.f + __expf(-acc));
}

// ===========================================================================
// FALLBACK PATH (global-atomic version) if ws_size is too small.
// ===========================================================================
__global__ __launch_bounds__(256) void k_prep1f(
    const float* __restrict__ x, const float* __restrict__ W1,
    const float* __restrict__ a_src, const float* __restrict__ a_dst,
    const float* __restrict__ resW, const float* __restrict__ resb,
    const unsigned* __restrict__ ei,
    float* __restrict__ resid, float* __restrict__ h1,
    float* __restrict__ asv, float* __restrict__ adv,
    float* __restrict__ num, float* __restrict__ den,
    float* __restrict__ sm, int* __restrict__ flag)
{
  __shared__ float sW1[64], sWr[64], sv[12];
  int t = threadIdx.x;
  if (t < 64) { sW1[t] = W1[t]; sWr[t] = resW[t]; }
  if (t < 4)  { sv[t] = a_src[t]; sv[4+t] = a_dst[t]; sv[8+t] = resb[t]; }
  __syncthreads();
  int i = blockIdx.x * 256 + t;
  if (i == 0) {
    sm[0]=0.f; sm[1]=0.f; sm[2]=0.f; sm[3]=0.f;
    int* smi = (int*)sm; smi[4]=0; smi[5]=0; smi[6]=0; smi[7]=0;
    unsigned o = 0;
    for (int k = 1; k < 64; k += 2) o |= ei[k];
    *flag = (o == 0) ? 1 : 0;
  }
  if (i >= NN) return;
  const float4* xp = (const float4*)(x + (size_t)i * 16);
  float4 a0 = xp[0], a1 = xp[1], a2 = xp[2], a3 = xp[3];
  float xr[16] = {a0.x,a0.y,a0.z,a0.w, a1.x,a1.y,a1.z,a1.w,
                  a2.x,a2.y,a2.z,a2.w, a3.x,a3.y,a3.z,a3.w};
  float h[4] = {0.f,0.f,0.f,0.f};
  float r[4] = {sv[8], sv[9], sv[10], sv[11]};
#pragma unroll
  for (int k = 0; k < 16; k++) {
    float xv = xr[k];
#pragma unroll
    for (int c = 0; c < 4; c++) {
      h[c] = fmaf(xv, sW1[k*4+c], h[c]);
      r[c] = fmaf(xv, sWr[k*4+c], r[c]);
    }
  }
  float as_ = h[0]*sv[0] + h[1]*sv[1] + h[2]*sv[2] + h[3]*sv[3];
  float ad_ = h[0]*sv[4] + h[1]*sv[5] + h[2]*sv[6] + h[3]*sv[7];
  float e = as_ + ad_;
  e = e > 0.f ? e : 0.2f * e;
  float ex = __expf(e);
  *(float4*)(resid + (size_t)i*4) = make_float4(r[0], r[1], r[2], r[3]);
  *(float4*)(h1    + (size_t)i*4) = make_float4(h[0], h[1], h[2], h[3]);
  asv[i] = as_; adv[i] = ad_;
  den[i] = ex;
  *(float4*)(num + (size_t)i*4) = make_float4(ex*h[0], ex*h[1], ex*h[2], ex*h[3]);
}

__global__ __launch_bounds__(256) void k_edgef(
    const unsigned* __restrict__ ei, const int* __restrict__ flag,
    const float* __restrict__ asv, const float* __restrict__ adv,
    const float* __restrict__ h, float* __restrict__ num, float* __restrict__ den)
{
  int e = blockIdx.x * 256 + threadIdx.x;
  if (e >= NE) return;
  int s, d;
  if (*flag) {
    s = (int)ei[2 * (size_t)e];
    d = (int)ei[2 * ((size_t)NE + (size_t)e)];
  } else {
    s = (int)ei[e];
    d = (int)ei[(size_t)NE + (size_t)e];
  }
  float v = asv[s] + adv[d];
  v = v > 0.f ? v : 0.2f * v;
  float ex = __expf(v);
  float4 hs = *(const float4*)(h + 4 * (size_t)s);
  float* np = num + 4 * (size_t)d;
  atomicAdd(den + d, ex);
  atomicAdd(np + 0, ex * hs.x);
  atomicAdd(np + 1, ex * hs.y);
  atomicAdd(np + 2, ex * hs.z);
  atomicAdd(np + 3, ex * hs.w);
}

__global__ __launch_bounds__(256) void k_finishf(
    const float* __restrict__ num, const float* __restrict__ den,
    const float* __restrict__ b, float* __restrict__ hout, float* __restrict__ pool)
{
  int i = blockIdx.x * 256 + threadIdx.x;
  float hv[4] = {0.f, 0.f, 0.f, 0.f};
  if (i < NN) {
    float inv = 1.f / den[i];
    float4 nm = *(const float4*)(num + (size_t)i*4);
    hv[0] = fmaxf(nm.x * inv + b[0], 0.f);
    hv[1] = fmaxf(nm.y * inv + b[1], 0.f);
    hv[2] = fmaxf(nm.z * inv + b[2], 0.f);
    hv[3] = fmaxf(nm.w * inv + b[3], 0.f);
    *(float4*)(hout + (size_t)i*4) = make_float4(hv[0], hv[1], hv[2], hv[3]);
  }
  float sv[4] = {hv[0], hv[1], hv[2], hv[3]};
  float mv[4] = {hv[0], hv[1], hv[2], hv[3]};
#pragma unroll
  for (int off = 32; off > 0; off >>= 1) {
#pragma unroll
    for (int c = 0; c < 4; c++) {
      sv[c] += __shfl_down(sv[c], off);
      mv[c] = fmaxf(mv[c], __shfl_down(mv[c], off));
    }
  }
  __shared__ float rs[4][4], rm[4][4];
  int w = threadIdx.x >> 6, lane = threadIdx.x & 63;
  if (lane == 0)
    for (int c = 0; c < 4; c++) { rs[w][c] = sv[c]; rm[w][c] = mv[c]; }
  __syncthreads();
  if (threadIdx.x == 0) {
    for (int c = 0; c < 4; c++) {
      float s0 = rs[0][c] + rs[1][c] + rs[2][c] + rs[3][c];
      float m0 = fmaxf(fmaxf(rm[0][c], rm[1][c]), fmaxf(rm[2][c], rm[3][c]));
      atomicAdd(pool + c, s0);
      atomicMax((int*)pool + 4 + c, __float_as_int(m0));
    }
  }
}

__global__ __launch_bounds__(256) void k_prep2f(
    const float* __restrict__ hin, const float* __restrict__ W2g,
    const float* __restrict__ a_src, const float* __restrict__ a_dst,
    float* __restrict__ h2, float* __restrict__ asv, float* __restrict__ adv,
    float* __restrict__ num, float* __restrict__ den, float* __restrict__ sm)
{
  __shared__ float sW[16], sa[8];
  int t = threadIdx.x;
  if (t < 16) sW[t] = W2g[t];
  if (t < 4) { sa[t] = a_src[t]; sa[4+t] = a_dst[t]; }
  __syncthreads();
  int i = blockIdx.x * 256 + t;
  if (i == 0) {
    sm[0]=0.f; sm[1]=0.f; sm[2]=0.f; sm[3]=0.f;
    int* smi = (int*)sm; smi[4]=0; smi[5]=0; smi[6]=0; smi[7]=0;
  }
  if (i >= NN) return;
  float4 hr = *(const float4*)(hin + (size_t)i*4);
  float hvv[4] = {hr.x, hr.y, hr.z, hr.w};
  float h[4] = {0.f, 0.f, 0.f, 0.f};
#pragma unroll
  for (int k = 0; k < 4; k++)
#pragma unroll
    for (int c = 0; c < 4; c++) h[c] = fmaf(hvv[k], sW[k*4+c], h[c]);
  float as_ = h[0]*sa[0] + h[1]*sa[1] + h[2]*sa[2] + h[3]*sa[3];
  float ad_ = h[0]*sa[4] + h[1]*sa[5] + h[2]*sa[6] + h[3]*sa[7];
  float e = as_ + ad_;
  e = e > 0.f ? e : 0.2f * e;
  float ex = __expf(e);
  *(float4*)(h2 + (size_t)i*4) = make_float4(h[0], h[1], h[2], h[3]);
  asv[i] = as_; adv[i] = ad_;
  den[i] = ex;
  *(float4*)(num + (size_t)i*4) = make_float4(ex*h[0], ex*h[1], ex*h[2], ex*h[3]);
}

// ===========================================================================
extern "C" void kernel_launch(void* const* d_in, const int* in_sizes, int n_in,
                              void* d_out, int out_size, void* d_ws, size_t ws_size,
                              hipStream_t stream)
{
  const float*    x    = (const float*)d_in[0];
  const unsigned* ei   = (const unsigned*)d_in[1];
  const float*    W1   = (const float*)d_in[2];
  const float*    as1  = (const float*)d_in[3];
  const float*    ad1  = (const float*)d_in[4];
  const float*    b1   = (const float*)d_in[5];
  const float*    W2   = (const float*)d_in[6];
  const float*    as2  = (const float*)d_in[7];
  const float*    ad2  = (const float*)d_in[8];
  const float*    b2   = (const float*)d_in[9];
  const float*    c1w1 = (const float*)d_in[10];
  const float*    c1w2 = (const float*)d_in[11];
  const float*    c2w1 = (const float*)d_in[12];
  const float*    c2w2 = (const float*)d_in[13];
  const float*    resW = (const float*)d_in[14];
  const float*    resb = (const float*)d_in[15];
  const float*    fcW  = (const float*)d_in[16];
  const float*    fcb  = (const float*)d_in[17];
  float* out = (float*)d_out;

  dim3 blk(256);
  dim3 gn((NN + 255) / 256);      // 1954
  dim3 ge((NE + 255) / 256);

  char* p = (char*)d_ws;
  auto alloc = [&](size_t bytes) { char* r = p; p += (bytes + 255) & ~(size_t)255; return r; };
  float*    resid = (float*)alloc((size_t)NN * 4 * 4);
  float2*   tab   = (float2*)alloc((size_t)NN * 8);
  float*    adv   = (float*)alloc((size_t)NN * 4);
  float*    hb    = (float*)alloc((size_t)NN * 4 * 4);
  float*    sm    = (float*)alloc(64 * 4);
  int*      flag  = (int*)alloc(256);
  int*      gcnt  = (int*)alloc((size_t)NBINS * 4);
  unsigned* edges = (unsigned*)alloc((size_t)NBINS * SUBCAP * 4);
  size_t need = (size_t)(p - (char*)d_ws);

  if (ws_size >= need) {
    hipLaunchKernelGGL(k_prep1, gn, blk, 0, stream, x, W1, ad1, resW, resb, ei,
                       resid, tab, adv, sm, flag, gcnt);
    hipLaunchKernelGGL(k_part, dim3(PBLK), blk, 0, stream, ei, flag, gcnt, edges);
    hipLaunchKernelGGL(k_reduce, dim3(NBUK), blk, 0, stream, edges, gcnt, tab, adv,
                       as1, b1, hb, sm);
    hipLaunchKernelGGL(k_gate1, dim3(1), dim3(64), 0, stream, sm, c1w1, c1w2, W2, sm + 8);
    hipLaunchKernelGGL(k_prep2, gn, blk, 0, stream, hb, sm + 8, ad2, tab, adv, sm);
    hipLaunchKernelGGL(k_reduce, dim3(NBUK), blk, 0, stream, edges, gcnt, tab, adv,
                       as2, b2, hb, sm);
    hipLaunchKernelGGL(k_gate2, dim3(1), dim3(64), 0, stream, sm, c2w1, c2w2, fcW, sm + 24);
    hipLaunchKernelGGL(k_final, gn, blk, 0, stream, hb, resid, sm + 24, fcW, fcb, out);
  } else {
    float* ws2   = (float*)d_ws;
    float* residf= ws2;  ws2 += (size_t)NN * 4;
    float* h1    = ws2;  ws2 += (size_t)NN * 4;
    float* asb   = ws2;  ws2 += NN;
    float* adb   = ws2;  ws2 += NN;
    float* num   = ws2;  ws2 += (size_t)NN * 4;
    float* den   = ws2;  ws2 += NN;
    float* hbf   = ws2;  ws2 += (size_t)NN * 4;
    float* smf   = ws2;  ws2 += 64;
    int* flagf = (int*)ws2;

    hipLaunchKernelGGL(k_prep1f, gn, blk, 0, stream, x, W1, as1, ad1, resW, resb, ei,
                       residf, h1, asb, adb, num, den, smf, flagf);
    hipLaunchKernelGGL(k_edgef, ge, blk, 0, stream, ei, flagf, asb, adb, h1, num, den);
    hipLaunchKernelGGL(k_finishf, gn, blk, 0, stream, num, den, b1, hbf, smf);
    hipLaunchKernelGGL(k_gate1, dim3(1), dim3(64), 0, stream, smf, c1w1, c1w2, W2, smf + 8);
    hipLaunchKernelGGL(k_prep2f, gn, blk, 0, stream, hbf, smf + 8, as2, ad2,
                       h1, asb, adb, num, den, smf);
    hipLaunchKernelGGL(k_edgef, ge, blk, 0, stream, ei, flagf, asb, adb, h1, num, den);
    hipLaunchKernelGGL(k_finishf, gn, blk, 0, stream, num, den, b2, hbf, smf);
    hipLaunchKernelGGL(k_gate2, dim3(1), dim3(64), 0, stream, smf, c2w1, c2w2, fcW, smf + 24);
    hipLaunchKernelGGL(k_final, gn, blk, 0, stream, hbf, residf, smf + 24, fcW, fcb, out);
  }
}